// Round 7
// baseline (427.242 us; speedup 1.0000x reference)
//
#include <hip/hip_runtime.h>
#include <hip/hip_bf16.h>

// CapsuleLayerWithRouting: batch=128, in_caps=1152, in_hid=16, out_caps=32,
// out_hid=16, 3 routing iterations (fixed). fp32 in/out.
//
// Round-7: 4 dispatches, no cooperative launch (round-6's coop kernel never
// launched -> output stayed zero). Same verified math as round 5:
//   transposed MFMA  D = W_tile . x^T  (per o-tile, K padded 16->32 with
//   zeros baked into x's upper lanes), one-barrier-per-i softmax, B-logit
//   linearity (pass3 uses V1+V2 -> no Bias array).
// New structure:
//   d1 conv_w : W -> bf16 A-fragments Wb; ALSO zeroes S1/S2/S3 + counter
//   d2 pass1  : C = 1/32 uniform; atomicAdd partial sums into S1
//   d3 pass2  : V1 = squash(S1) computed per-thread at start (float4 row +
//               2 shuffles); dot/softmax/accum; atomicAdd into S2
//   d4 pass3  : V = squash(S1)+squash(S2); accum into S3; last-finishing
//               block (threadfence+counter) squashes S3 -> d_out
// Fragment layouts (HW-verified m89/m91):
//   A[m=lane&15][k=(lane>>4)*8+j]  B[k=(lane>>4)*8+j][n=lane&15]
//   D[row=(lane>>4)*4+reg][col=lane&15]

#define IN_CAPS 1152
#define IPC 18
#define NBLK_I 64                            // 1152/18
#define SV_ELEMS 65536                       // 128*32*16

typedef __attribute__((ext_vector_type(8))) short short8;
typedef __attribute__((ext_vector_type(4))) float f32x4;

__device__ inline unsigned f2bf(float x) {   // RNE fp32 -> bf16
  unsigned u = __builtin_bit_cast(unsigned, x);
  return (u + 0x7FFFu + ((u >> 16) & 1u)) >> 16;
}

// ---- d1: W [1152][16][512] fp32 -> Wb [i][o][lane(32)][8] bf16 (A-frag);
// LDS-staged so reads and writes are both coalesced. Also zero-inits the
// S region (harness re-poisons ws to 0xAA before every launch).
__global__ __launch_bounds__(256)
void conv_w(const float* __restrict__ W, unsigned short* __restrict__ Wb,
            float* __restrict__ Szero, unsigned* __restrict__ counter) {
  __shared__ float st[16 * 516];              // stride 516: minimal conflicts
  const int t = threadIdx.x;
  if (blockIdx.x < 192) {                     // 192*256 float4 = 196608 floats
    ((float4*)Szero)[blockIdx.x * 256 + t] = make_float4(0.f, 0.f, 0.f, 0.f);
  }
  if (blockIdx.x == 192 && t < 16) counter[t] = 0u;

  const size_t ibase = (size_t)blockIdx.x * 8192;
  const float4* src = (const float4*)(W + ibase);
#pragma unroll
  for (int r = 0; r < 8; ++r) {
    const int f = r * 256 + t;                // 0..2047 float4s
    const int k = f >> 7, c4 = f & 127;
    *(float4*)&st[k * 516 + c4 * 4] = src[f];
  }
  __syncthreads();
  unsigned short* dst = Wb + ibase;
#pragma unroll
  for (int r = 0; r < 4; ++r) {
    const int u = r * 256 + t;                // 0..1023 = o*32 + l
    const int o = u >> 5, l = u & 31;
    const int col = o * 16 + (l & 15), k0 = (l >> 4) * 8;
    unsigned b[8];
#pragma unroll
    for (int j = 0; j < 8; ++j) b[j] = f2bf(st[(k0 + j) * 516 + col]);
    uint4 outv;
    outv.x = b[0] | (b[1] << 16);
    outv.y = b[2] | (b[3] << 16);
    outv.z = b[4] | (b[5] << 16);
    outv.w = b[6] | (b[7] << 16);
    *(uint4*)(dst + (size_t)u * 8) = outv;    // consecutive u -> coalesced
  }
}

// ---- x B-fragment slice in LDS; zeros in lanes 32-63 (K pad 16->32) ----
__device__ __forceinline__ void build_xs(const float* __restrict__ X, int bg,
                                         int i0, int t, unsigned (*xs)[64][4]) {
#pragma unroll
  for (int rep = 0; rep < (IPC * 256) / 512; ++rep) {   // 9
    const int base = rep * 512 + t;
    const int ii = base >> 8;
    const int e = base & 255;
    const int l2 = e >> 2, ju = e & 3;
    unsigned val = 0;
    if (l2 < 32) {
      const float2 f = *(const float2*)(X +
          ((size_t)(bg * 16 + (l2 & 15)) * IN_CAPS + (i0 + ii)) * 16 +
          (l2 >> 4) * 8 + 2 * ju);
      val = f2bf(f.x) | (f2bf(f.y) << 16);
    }
    xs[ii][l2][ju] = val;
  }
}

__device__ __forceinline__ short8 ld_x(const unsigned (*xs)[64][4], int ii, int l) {
  return __builtin_bit_cast(short8, *(const uint4*)(&xs[ii][l][0]));
}

// squash row fragment: thread (q,bl,w,m) loads S[b][o][q*4..q*4+3]; row norm
// via 2 shuffles over the q-lanes (l, l^16, l^32, l^48 share b,o).
__device__ __forceinline__ f32x4 vfrag(const float* __restrict__ Srow, int m) {
  f32x4 s4 = *(const f32x4*)(Srow + m * 16);
  float ns = (s4[0] * s4[0] + s4[1] * s4[1]) + (s4[2] * s4[2] + s4[3] * s4[3]);
  ns += __shfl_xor(ns, 16);
  ns += __shfl_xor(ns, 32);
  const float sc = ns / ((1.f + ns) * sqrtf(ns));
  return s4 * sc;
}

// ---- pass kernel. PASS 1: C=1/32 uniform. PASS 2: V=squash(S1).
// PASS 3: V=squash(S1)+squash(S2), plus last-block squash(S3)->Out tail. ----
template <int PASS>
__global__ __launch_bounds__(512, 4)
void caps_pass(const unsigned short* __restrict__ Wb,
               const float* __restrict__ X,
               const float* __restrict__ S1, const float* __restrict__ S2,
               float* __restrict__ Scur, unsigned* __restrict__ counter,
               float* __restrict__ Out) {
  __shared__ __align__(16) unsigned xs[IPC][64][4];
  __shared__ float part[2][8][16];
  __shared__ unsigned lastFlag;

  const int t = threadIdx.x, w = t >> 6, l = t & 63;
  const int q = l >> 4, bl = l & 15;
  const int bx = blockIdx.x, iblk = bx & 63, bg = bx >> 6;
  const int i0 = iblk * IPC;

  f32x4 v[4], sacc[4];
#pragma unroll
  for (int m = 0; m < 4; ++m) sacc[m] = (f32x4){0.f, 0.f, 0.f, 0.f};
  if constexpr (PASS >= 2) {
    const size_t rbase = ((size_t)(bg * 16 + bl) * 32 + w * 4) * 16 + q * 4;
#pragma unroll
    for (int m = 0; m < 4; ++m) {
      v[m] = vfrag(S1 + rbase, m);
      if constexpr (PASS == 3) v[m] += vfrag(S2 + rbase, m);
    }
  }

  build_xs(X, bg, i0, t, xs);
  __syncthreads();

  const short8* wp = (const short8*)Wb + ((size_t)i0 * 32 + w * 4) * 32 + (l & 31);

  if constexpr (PASS == 1) {
    for (int ii = 0; ii < IPC; ++ii) {
      short8 x = ld_x(xs, ii, l);
      short8 a0 = wp[0], a1 = wp[32], a2 = wp[64], a3 = wp[96];
      wp += 1024;
      sacc[0] = __builtin_amdgcn_mfma_f32_16x16x32_bf16(a0, x, sacc[0], 0, 0, 0);
      sacc[1] = __builtin_amdgcn_mfma_f32_16x16x32_bf16(a1, x, sacc[1], 0, 0, 0);
      sacc[2] = __builtin_amdgcn_mfma_f32_16x16x32_bf16(a2, x, sacc[2], 0, 0, 0);
      sacc[3] = __builtin_amdgcn_mfma_f32_16x16x32_bf16(a3, x, sacc[3], 0, 0, 0);
    }
  } else {
    short8 an[4];
    short8 xn = ld_x(xs, 0, l);
#pragma unroll
    for (int m = 0; m < 4; ++m) an[m] = wp[m * 32];
    wp += 1024;

    for (int ii = 0; ii < IPC; ++ii) {
      short8 ac[4];
#pragma unroll
      for (int m = 0; m < 4; ++m) ac[m] = an[m];
      short8 xc = xn;
      if (ii + 1 < IPC) {                    // prefetch rides across barrier
        xn = ld_x(xs, ii + 1, l);
#pragma unroll
        for (int m = 0; m < 4; ++m) an[m] = wp[m * 32];
        wp += 1024;
      }

      const f32x4 z = {0.f, 0.f, 0.f, 0.f};
      f32x4 d[4];
#pragma unroll
      for (int m = 0; m < 4; ++m)
        d[m] = __builtin_amdgcn_mfma_f32_16x16x32_bf16(ac[m], xc, z, 0, 0, 0);
      // d[m][r] = U[o=w*4+m][h=q*4+r][b=bl]

      float e[4];
#pragma unroll
      for (int m = 0; m < 4; ++m) {
        f32x4 pr = d[m] * v[m];
        float p = (pr[0] + pr[1]) + (pr[2] + pr[3]);
        p += __shfl_xor(p, 16);
        p += __shfl_xor(p, 32);
        e[m] = __expf(p);
      }
      const float esum = (e[0] + e[1]) + (e[2] + e[3]);
      if (q == 0) part[ii & 1][w][bl] = esum;
      __syncthreads();
      float den = 0.f;
#pragma unroll
      for (int ww = 0; ww < 8; ++ww) den += part[ii & 1][ww][bl];
      const float rden = __builtin_amdgcn_rcpf(den);
#pragma unroll
      for (int m = 0; m < 4; ++m) sacc[m] += d[m] * (e[m] * rden);
      // part[parity] reuse two iters later is fenced by the barrier between
    }
  }

  // ---- atomic flush into Scur (each S element touched once per block) ----
  float* sp = Scur + ((size_t)(bg * 16 + bl) * 512) + w * 64 + q * 4;
#pragma unroll
  for (int m = 0; m < 4; ++m)
#pragma unroll
    for (int r = 0; r < 4; ++r) {
      float val = sacc[m][r];
      if constexpr (PASS == 1) val *= (1.f / 32.f);
      atomicAdd(sp + m * 16 + r, val);
    }

  if constexpr (PASS == 3) {
    // last-finishing block squashes S3 -> Out (canonical threadfence pattern)
    __threadfence();
    __syncthreads();
    if (t == 0) lastFlag = (atomicAdd(counter, 1u) == 511u) ? 1u : 0u;
    __syncthreads();
    if (lastFlag) {
      __threadfence();
#pragma unroll
      for (int rr = 0; rr < 8; ++rr) {
        const int row = rr * 512 + t;        // 4096 rows
        const f32x4* s = (const f32x4*)(Scur + (size_t)row * 16);
        f32x4 s0 = s[0], s1 = s[1], s2 = s[2], s3 = s[3];
        float ns = (s0[0]*s0[0]+s0[1]*s0[1]+s0[2]*s0[2]+s0[3]*s0[3])
                 + (s1[0]*s1[0]+s1[1]*s1[1]+s1[2]*s1[2]+s1[3]*s1[3])
                 + (s2[0]*s2[0]+s2[1]*s2[1]+s2[2]*s2[2]+s2[3]*s2[3])
                 + (s3[0]*s3[0]+s3[1]*s3[1]+s3[2]*s3[2]+s3[3]*s3[3]);
        const float sc = ns / ((1.f + ns) * sqrtf(ns));
        f32x4* op = (f32x4*)(Out + (size_t)row * 16);
        op[0] = s0 * sc; op[1] = s1 * sc; op[2] = s2 * sc; op[3] = s3 * sc;
      }
    }
  }
}

extern "C" void kernel_launch(void* const* d_in, const int* in_sizes, int n_in,
                              void* d_out, int out_size, void* d_ws, size_t ws_size,
                              hipStream_t stream) {
  const float* X  = (const float*)d_in[0];
  const float* Wg = (const float*)d_in[1];
  // d_in[2] = routing_iterations (3, hard-coded)

  float* S1 = (float*)d_ws;                         // 65536 f
  float* S2 = S1 + SV_ELEMS;                        // 65536 f
  float* S3 = S2 + SV_ELEMS;                        // 65536 f
  unsigned* counter = (unsigned*)(S3 + SV_ELEMS);   // 16 u32 (zeroed w/ S)
  unsigned short* Wb = (unsigned short*)(S1 + 196672);  // 18.9 MB, 16B-aligned
  float* out = (float*)d_out;                       // total ws ~19.7 MB

  conv_w<<<IN_CAPS, 256, 0, stream>>>(Wg, Wb, S1, counter);
  caps_pass<1><<<512, 512, 0, stream>>>(Wb, X, nullptr, nullptr, S1, nullptr, nullptr);
  caps_pass<2><<<512, 512, 0, stream>>>(Wb, X, S1, nullptr, S2, nullptr, nullptr);
  caps_pass<3><<<512, 512, 0, stream>>>(Wb, X, S1, S2, S3, counter, out);
}

// Round 8
// 250.702 us; speedup vs baseline: 1.7042x; 1.7042x over previous
//
#include <hip/hip_runtime.h>
#include <hip/hip_bf16.h>

// CapsuleLayerWithRouting: batch=128, in_caps=1152, in_hid=16, out_caps=32,
// out_hid=16, 3 routing iterations (fixed). fp32 in/out.
//
// Round-8: round-7 structure (4 dispatches: conv_w + 3 fused pass kernels,
// in-kernel squash recompute, B-logit linearity, last-block output tail) with
// the atomic flush FIXED: round-7 flushed with lane-stride-512 addresses
// (64 cachelines per wave instruction -> WRITE_SIZE 65.8MB, 153us/pass).
// Now sacc is staged through LDS (union with the dead xs buffer) and
// re-read transposed so atomics are lane-consecutive (64 contiguous floats
// per wave instruction), the round-3-proven pattern.
// Fragment layouts (HW-verified m89/m91):
//   A[m=lane&15][k=(lane>>4)*8+j]  B[k=(lane>>4)*8+j][n=lane&15]
//   D[row=(lane>>4)*4+reg][col=lane&15];  K padded 16->32 via zeros in xs.

#define IN_CAPS 1152
#define IPC 18
#define NBLK_I 64                            // 1152/18
#define SV_ELEMS 65536                       // 128*32*16

typedef __attribute__((ext_vector_type(8))) short short8;
typedef __attribute__((ext_vector_type(4))) float f32x4;

__device__ inline unsigned f2bf(float x) {   // RNE fp32 -> bf16
  unsigned u = __builtin_bit_cast(unsigned, x);
  return (u + 0x7FFFu + ((u >> 16) & 1u)) >> 16;
}

// ---- d1: W [1152][16][512] fp32 -> Wb [i][o][lane(32)][8] bf16 (A-frag);
// LDS-staged so reads and writes are both coalesced. Also zero-inits S1/S2/S3
// + counter (harness re-poisons ws to 0xAA before every launch).
__global__ __launch_bounds__(256)
void conv_w(const float* __restrict__ W, unsigned short* __restrict__ Wb,
            float* __restrict__ Szero, unsigned* __restrict__ counter) {
  __shared__ float st[16 * 516];
  const int t = threadIdx.x;
  if (blockIdx.x < 192) {                     // 192*256 float4 = 196608 floats
    ((float4*)Szero)[blockIdx.x * 256 + t] = make_float4(0.f, 0.f, 0.f, 0.f);
  }
  if (blockIdx.x == 192 && t < 16) counter[t] = 0u;

  const size_t ibase = (size_t)blockIdx.x * 8192;
  const float4* src = (const float4*)(W + ibase);
#pragma unroll
  for (int r = 0; r < 8; ++r) {
    const int f = r * 256 + t;                // 0..2047 float4s
    const int k = f >> 7, c4 = f & 127;
    *(float4*)&st[k * 516 + c4 * 4] = src[f];
  }
  __syncthreads();
  unsigned short* dst = Wb + ibase;
#pragma unroll
  for (int r = 0; r < 4; ++r) {
    const int u = r * 256 + t;                // 0..1023 = o*32 + l
    const int o = u >> 5, l = u & 31;
    const int col = o * 16 + (l & 15), k0 = (l >> 4) * 8;
    unsigned b[8];
#pragma unroll
    for (int j = 0; j < 8; ++j) b[j] = f2bf(st[(k0 + j) * 516 + col]);
    uint4 outv;
    outv.x = b[0] | (b[1] << 16);
    outv.y = b[2] | (b[3] << 16);
    outv.z = b[4] | (b[5] << 16);
    outv.w = b[6] | (b[7] << 16);
    *(uint4*)(dst + (size_t)u * 8) = outv;    // consecutive u -> coalesced
  }
}

// ---- x B-fragment slice in LDS; zeros in lanes 32-63 (K pad 16->32) ----
__device__ __forceinline__ void build_xs(const float* __restrict__ X, int bg,
                                         int i0, int t, unsigned (*xs)[64][4]) {
#pragma unroll
  for (int rep = 0; rep < (IPC * 256) / 512; ++rep) {   // 9
    const int base = rep * 512 + t;
    const int ii = base >> 8;
    const int e = base & 255;
    const int l2 = e >> 2, ju = e & 3;
    unsigned val = 0;
    if (l2 < 32) {
      const float2 f = *(const float2*)(X +
          ((size_t)(bg * 16 + (l2 & 15)) * IN_CAPS + (i0 + ii)) * 16 +
          (l2 >> 4) * 8 + 2 * ju);
      val = f2bf(f.x) | (f2bf(f.y) << 16);
    }
    xs[ii][l2][ju] = val;
  }
}

__device__ __forceinline__ short8 ld_x(const unsigned (*xs)[64][4], int ii, int l) {
  return __builtin_bit_cast(short8, *(const uint4*)(&xs[ii][l][0]));
}

// squash row fragment: thread (q,bl,w,m) loads S[b][o][q*4..q*4+3]; row norm
// via 2 shuffles over lanes l^16, l^32 (same b,o).
__device__ __forceinline__ f32x4 vfrag(const float* __restrict__ Srow, int m) {
  f32x4 s4 = *(const f32x4*)(Srow + m * 16);
  float ns = (s4[0] * s4[0] + s4[1] * s4[1]) + (s4[2] * s4[2] + s4[3] * s4[3]);
  ns += __shfl_xor(ns, 16);
  ns += __shfl_xor(ns, 32);
  const float sc = ns / ((1.f + ns) * sqrtf(ns));
  return s4 * sc;
}

// ---- pass kernel. PASS 1: C=1/32 uniform. PASS 2: V=squash(S1).
// PASS 3: V=squash(S1)+squash(S2), plus last-block squash(S3)->Out tail. ----
template <int PASS>
__global__ __launch_bounds__(512, 4)
void caps_pass(const unsigned short* __restrict__ Wb,
               const float* __restrict__ X,
               const float* __restrict__ S1, const float* __restrict__ S2,
               float* __restrict__ Scur, unsigned* __restrict__ counter,
               float* __restrict__ Out) {
  __shared__ __align__(16) union {
    unsigned xs[IPC][64][4];   // 18.4 KB, i-loop only
    float flush[8252];         // 33.0 KB, post-loop staging (stride-516 rows)
  } u;
  __shared__ float part[2][8][16];
  __shared__ unsigned lastFlag;

  const int t = threadIdx.x, w = t >> 6, l = t & 63;
  const int q = l >> 4, bl = l & 15;
  const int bx = blockIdx.x, iblk = bx & 63, bg = bx >> 6;
  const int i0 = iblk * IPC;

  f32x4 v[4], sacc[4];
#pragma unroll
  for (int m = 0; m < 4; ++m) sacc[m] = (f32x4){0.f, 0.f, 0.f, 0.f};
  if constexpr (PASS >= 2) {
    const size_t rbase = ((size_t)(bg * 16 + bl) * 32 + w * 4) * 16 + q * 4;
#pragma unroll
    for (int m = 0; m < 4; ++m) {
      v[m] = vfrag(S1 + rbase, m);
      if constexpr (PASS == 3) v[m] += vfrag(S2 + rbase, m);
    }
  }

  build_xs(X, bg, i0, t, u.xs);
  __syncthreads();

  const short8* wp = (const short8*)Wb + ((size_t)i0 * 32 + w * 4) * 32 + (l & 31);

  if constexpr (PASS == 1) {
    for (int ii = 0; ii < IPC; ++ii) {
      short8 x = ld_x(u.xs, ii, l);
      short8 a0 = wp[0], a1 = wp[32], a2 = wp[64], a3 = wp[96];
      wp += 1024;
      sacc[0] = __builtin_amdgcn_mfma_f32_16x16x32_bf16(a0, x, sacc[0], 0, 0, 0);
      sacc[1] = __builtin_amdgcn_mfma_f32_16x16x32_bf16(a1, x, sacc[1], 0, 0, 0);
      sacc[2] = __builtin_amdgcn_mfma_f32_16x16x32_bf16(a2, x, sacc[2], 0, 0, 0);
      sacc[3] = __builtin_amdgcn_mfma_f32_16x16x32_bf16(a3, x, sacc[3], 0, 0, 0);
    }
  } else {
    short8 an[4];
    short8 xn = ld_x(u.xs, 0, l);
#pragma unroll
    for (int m = 0; m < 4; ++m) an[m] = wp[m * 32];
    wp += 1024;

    for (int ii = 0; ii < IPC; ++ii) {
      short8 ac[4];
#pragma unroll
      for (int m = 0; m < 4; ++m) ac[m] = an[m];
      short8 xc = xn;
      if (ii + 1 < IPC) {                    // prefetch rides across barrier
        xn = ld_x(u.xs, ii + 1, l);
#pragma unroll
        for (int m = 0; m < 4; ++m) an[m] = wp[m * 32];
        wp += 1024;
      }

      const f32x4 z = {0.f, 0.f, 0.f, 0.f};
      f32x4 d[4];
#pragma unroll
      for (int m = 0; m < 4; ++m)
        d[m] = __builtin_amdgcn_mfma_f32_16x16x32_bf16(ac[m], xc, z, 0, 0, 0);
      // d[m][r] = U[o=w*4+m][h=q*4+r][b=bl]

      float e[4];
#pragma unroll
      for (int m = 0; m < 4; ++m) {
        f32x4 pr = d[m] * v[m];
        float p = (pr[0] + pr[1]) + (pr[2] + pr[3]);
        p += __shfl_xor(p, 16);
        p += __shfl_xor(p, 32);
        e[m] = __expf(p);
      }
      const float esum = (e[0] + e[1]) + (e[2] + e[3]);
      if (q == 0) part[ii & 1][w][bl] = esum;
      __syncthreads();
      float den = 0.f;
#pragma unroll
      for (int ww = 0; ww < 8; ++ww) den += part[ii & 1][ww][bl];
      const float rden = __builtin_amdgcn_rcpf(den);
#pragma unroll
      for (int m = 0; m < 4; ++m) sacc[m] += d[m] * (e[m] * rden);
      // part[parity] reuse two iters later is fenced by the barrier between
    }
  }

  // ---- flush: stage sacc in LDS, re-read transposed, coalesced atomics ----
  __syncthreads();                           // xs dead; flush aliases it
#pragma unroll
  for (int m = 0; m < 4; ++m) {
    f32x4 val = sacc[m];
    if constexpr (PASS == 1) val *= (1.f / 32.f);
    // row bl (stride 516), inner = o*16+h = (4w+m)*16 + 4q + r (r packed in b128)
    *(f32x4*)&u.flush[bl * 516 + (4 * w + m) * 16 + 4 * q] = val;
  }
  __syncthreads();
  float* sp = Scur + (size_t)(bg * 16) * 512 + t;
#pragma unroll
  for (int k = 0; k < 16; ++k)               // lanes consecutive -> coalesced
    atomicAdd(sp + (size_t)k * 512, u.flush[k * 516 + t]);

  if constexpr (PASS == 3) {
    // last-finishing block squashes S3 -> Out (threadfence+counter pattern)
    __threadfence();
    __syncthreads();
    if (t == 0) lastFlag = (atomicAdd(counter, 1u) == 511u) ? 1u : 0u;
    __syncthreads();
    if (lastFlag) {
      __threadfence();
#pragma unroll
      for (int rr = 0; rr < 8; ++rr) {
        const int row = rr * 512 + t;        // 4096 rows
        const f32x4* s = (const f32x4*)(Scur + (size_t)row * 16);
        f32x4 s0 = s[0], s1 = s[1], s2 = s[2], s3 = s[3];
        float ns = (s0[0]*s0[0]+s0[1]*s0[1]+s0[2]*s0[2]+s0[3]*s0[3])
                 + (s1[0]*s1[0]+s1[1]*s1[1]+s1[2]*s1[2]+s1[3]*s1[3])
                 + (s2[0]*s2[0]+s2[1]*s2[1]+s2[2]*s2[2]+s2[3]*s2[3])
                 + (s3[0]*s3[0]+s3[1]*s3[1]+s3[2]*s3[2]+s3[3]*s3[3]);
        const float sc = ns / ((1.f + ns) * sqrtf(ns));
        f32x4* op = (f32x4*)(Out + (size_t)row * 16);
        op[0] = s0 * sc; op[1] = s1 * sc; op[2] = s2 * sc; op[3] = s3 * sc;
      }
    }
  }
}

extern "C" void kernel_launch(void* const* d_in, const int* in_sizes, int n_in,
                              void* d_out, int out_size, void* d_ws, size_t ws_size,
                              hipStream_t stream) {
  const float* X  = (const float*)d_in[0];
  const float* Wg = (const float*)d_in[1];
  // d_in[2] = routing_iterations (3, hard-coded)

  float* S1 = (float*)d_ws;                         // 65536 f
  float* S2 = S1 + SV_ELEMS;                        // 65536 f
  float* S3 = S2 + SV_ELEMS;                        // 65536 f
  unsigned* counter = (unsigned*)(S3 + SV_ELEMS);   // 16 u32 (zeroed w/ S)
  unsigned short* Wb = (unsigned short*)(S1 + 196672);  // 18.9 MB, 16B-aligned
  float* out = (float*)d_out;                       // total ws ~19.7 MB

  conv_w<<<IN_CAPS, 256, 0, stream>>>(Wg, Wb, S1, counter);
  caps_pass<1><<<512, 512, 0, stream>>>(Wb, X, nullptr, nullptr, S1, nullptr, nullptr);
  caps_pass<2><<<512, 512, 0, stream>>>(Wb, X, S1, nullptr, S2, nullptr, nullptr);
  caps_pass<3><<<512, 512, 0, stream>>>(Wb, X, S1, S2, S3, counter, out);
}